// Round 13
// baseline (1906.539 us; speedup 1.0000x reference)
//
#include <hip/hip_runtime.h>
#include <hip/hip_bf16.h>

#define C_IN  512
#define C_HID 256
#define C_OUT 64
#define K_STEPS 10
#define ALPHA 0.1f

#define BKT_SHIFT 9          // 512 nodes per bucket
#define BKT_NODES 512
#define BCAP 24576           // per-bucket edge capacity (mean 16384 -> huge margin)
#define EPB 4096             // edges per block in pass A (16 per thread)

typedef _Float16 half8 __attribute__((ext_vector_type(8)));
typedef float f32x4 __attribute__((ext_vector_type(4)));

// ---------------------------------------------------------------------------
// CSR build via two-level counting sort (write-locality-friendly)
// ---------------------------------------------------------------------------

__global__ __launch_bounds__(256) void k_bucketA(
    const int* __restrict__ src, const int* __restrict__ dst, int E,
    int* __restrict__ bcursor, long long* __restrict__ bedges, int nbkt)
{
    __shared__ int lcount[256];
    __shared__ int lbase[256];
    int t = threadIdx.x;
    int base = blockIdx.x * EPB;
    for (int i = t; i < nbkt; i += 256) lcount[i] = 0;
    __syncthreads();

    int       mybkt[16];
    int       myoff[16];
    long long mypk[16];
    #pragma unroll
    for (int j = 0; j < 16; j++) {
        int e = base + j * 256 + t;          // coalesced
        if (e < E) {
            int s = src[e], d = dst[e];
            int b = d >> BKT_SHIFT;
            mybkt[j] = b;
            mypk[j]  = ((long long)d << 32) | (unsigned int)s;
            myoff[j] = atomicAdd(&lcount[b], 1);
        } else {
            mybkt[j] = -1;
        }
    }
    __syncthreads();
    for (int i = t; i < nbkt; i += 256)
        lbase[i] = lcount[i] ? atomicAdd(&bcursor[i], lcount[i]) : 0;
    __syncthreads();
    #pragma unroll
    for (int j = 0; j < 16; j++) {
        if (mybkt[j] >= 0) {
            int p = lbase[mybkt[j]] + myoff[j];
            bedges[(size_t)mybkt[j] * BCAP + p] = mypk[j];
        }
    }
}

__global__ __launch_bounds__(256) void k_bcount(
    const int* __restrict__ bcursor, const long long* __restrict__ bedges,
    int* __restrict__ counts, int N)
{
    __shared__ int lcnt[BKT_NODES];
    int b = blockIdx.x, t = threadIdx.x;
    int nodebase = b << BKT_SHIFT;
    for (int i = t; i < BKT_NODES; i += 256) lcnt[i] = 0;
    __syncthreads();
    int cnt = bcursor[b];
    const long long* be = bedges + (size_t)b * BCAP;
    for (int i = t; i < cnt; i += 256) {
        int d = (int)(be[i] >> 32);
        atomicAdd(&lcnt[d - nodebase], 1);
    }
    __syncthreads();
    for (int i = t; i < BKT_NODES; i += 256) {
        int node = nodebase + i;
        if (node < N) counts[node] = lcnt[i];
    }
}

__global__ __launch_bounds__(256) void k_bscatter(
    const int* __restrict__ bcursor, const long long* __restrict__ bedges,
    const int* __restrict__ rowptr, int* __restrict__ csr_src, int N)
{
    __shared__ int lcur[BKT_NODES];
    int b = blockIdx.x, t = threadIdx.x;
    int nodebase = b << BKT_SHIFT;
    for (int i = t; i < BKT_NODES; i += 256) {
        int node = nodebase + i;
        lcur[i] = (node < N) ? rowptr[node] : 0;
    }
    __syncthreads();
    int cnt = bcursor[b];
    const long long* be = bedges + (size_t)b * BCAP;
    for (int i = t; i < cnt; i += 256) {
        long long pk = be[i];
        int d = (int)(pk >> 32);
        int s = (int)pk;
        int p = atomicAdd(&lcur[d - nodebase], 1);
        csr_src[p] = s;
    }
}

// ---------------------------------------------------------------------------
// dinv + rowptr scan
// ---------------------------------------------------------------------------

__global__ void k_dinv(const int* __restrict__ counts, float* __restrict__ dinv, int N) {
    int i = blockIdx.x * blockDim.x + threadIdx.x;
    if (i < N) {
        float deg = (float)(counts[i] + 1);   // +1 self-loop
        dinv[i] = 1.0f / sqrtf(deg);
    }
}

#define SCAN_CHUNK 2048

__global__ void k_scan1(const int* __restrict__ counts, int N, int* __restrict__ bsum) {
    __shared__ int sdata[256];
    int b = blockIdx.x, t = threadIdx.x;
    int base = b * SCAN_CHUNK;
    int sum = 0;
    for (int i = t; i < SCAN_CHUNK; i += 256) {
        int idx = base + i;
        sum += (idx < N) ? counts[idx] : 0;
    }
    sdata[t] = sum;
    __syncthreads();
    for (int off = 128; off; off >>= 1) {
        if (t < off) sdata[t] += sdata[t + off];
        __syncthreads();
    }
    if (t == 0) bsum[b] = sdata[0];
}

__global__ void k_scan2(int* __restrict__ bsum, int nb, int E, int* __restrict__ rowptr, int N) {
    if (blockIdx.x == 0 && threadIdx.x == 0) {
        int run = 0;
        for (int i = 0; i < nb; i++) { int v = bsum[i]; bsum[i] = run; run += v; }
        rowptr[N] = E;
    }
}

__global__ void k_scan3(const int* __restrict__ counts, int N,
                        const int* __restrict__ bsum, int* __restrict__ rowptr) {
    __shared__ int sdata[256];
    int b = blockIdx.x, t = threadIdx.x;
    int base = b * SCAN_CHUNK;
    int vals[8];
    int local = 0;
    #pragma unroll
    for (int i = 0; i < 8; i++) {
        int idx = base + t * 8 + i;
        vals[i] = (idx < N) ? counts[idx] : 0;
        local += vals[i];
    }
    sdata[t] = local;
    __syncthreads();
    for (int off = 1; off < 256; off <<= 1) {
        int y = 0;
        if (t >= off) y = sdata[t - off];
        __syncthreads();
        sdata[t] += y;
        __syncthreads();
    }
    int excl = (t == 0) ? 0 : sdata[t - 1];
    int run = bsum[b] + excl;
    #pragma unroll
    for (int i = 0; i < 8; i++) {
        int idx = base + t * 8 + i;
        if (idx < N) rowptr[idx] = run;
        run += vals[i];
    }
}

// ---------------------------------------------------------------------------
// Weight pre-transpose + f16 conversion: W [K][N] f32 -> Wt [N][K] f16
// ---------------------------------------------------------------------------

__global__ void k_w1t(const float* __restrict__ W, _Float16* __restrict__ Wt) {
    int i = blockIdx.x * 256 + threadIdx.x;          // over 512*256
    int k = i >> 8, n = i & 255;
    Wt[(size_t)n * 512 + k] = (_Float16)W[i];
}

__global__ void k_w2t(const float* __restrict__ W, _Float16* __restrict__ Wt) {
    int i = blockIdx.x * 256 + threadIdx.x;          // over 256*64
    int k = i >> 6, n = i & 63;
    Wt[(size_t)n * 256 + k] = (_Float16)W[i];
}

// ---------------------------------------------------------------------------
// MLP layer 1 (counted-vmcnt pipeline, 128-thr blocks for stall decorrelation)
// hmid = relu(x @ W1 + b1). BM=64, BN=256 (x read ONCE), BK=32, 16 K-steps.
// 3 x 8KB LDS buffers; 24KB/block -> 6 independent blocks/CU (6 decorrelated
// barriers vs r12's single-barrier 2-block config). 2 waves (wc 0/1), each
// wave = 64 rows x 128 cols, acc[4][8] (=128 AGPR; +arch ~108 fits the
// 256-reg cap at (128,2) -- do NOT raise min-waves, r10 spill lesson).
// ---------------------------------------------------------------------------

__global__ __launch_bounds__(128, 2) void k_mlp1(
    const float* __restrict__ A, const _Float16* __restrict__ Bt,
    const float* __restrict__ bias, _Float16* __restrict__ C, int M)
{
    __shared__ float lds[3][64 * 32];    // 3 x 8KB

    int t    = threadIdx.x;              // 0..127
    int lane = t & 63;
    int wc   = t >> 6;                   // wave col (0..1) -> cols 128*wc
    int bm   = blockIdx.x * 64;
    int mrow = lane & 15;
    int kg   = lane >> 4;                // 0..3

    // staging: LDS chunk (q*128 + t) <- row r = q*16 + (t>>3), pos c = t&7,
    // src chunk cg = c ^ (r&7) = (t&7) ^ ((t>>3)&7)   (q*16 = 0 mod 8)
    int srow = t >> 3;                   // 0..15, + 16*q
    int cgs  = (t & 7) ^ ((t >> 3) & 7);

    const float* gsrc[4];
    #pragma unroll
    for (int q = 0; q < 4; q++) {
        int gr = bm + q * 16 + srow;
        if (gr >= M) gr = M - 1;         // clamp: no OOB reads, rows discarded at C-write
        gsrc[q] = A + (size_t)gr * 512 + cgs * 4;
    }

    #define STAGE(buf, ks)                                                       \
        {                                                                        \
            _Pragma("unroll")                                                    \
            for (int q = 0; q < 4; q++) {                                        \
                __builtin_amdgcn_global_load_lds(                                \
                    (const __attribute__((address_space(1))) void*)(gsrc[q] + (ks) * 32), \
                    (__attribute__((address_space(3))) void*)((char*)&lds[buf][0] + q * 2048 + t * 16), \
                    16, 0, 0);                                                   \
            }                                                                    \
        }

    f32x4 acc[4][8] = {};

    // read-side swizzle: row_local&7 == mrow&7 for all mi (offsets mult of 8)
    int m7 = lane & 7;
    int rbase[4];
    #pragma unroll
    for (int mi = 0; mi < 4; mi++)
        rbase[mi] = (mi * 16 + mrow) * 32;
    int p0 = ((2 * kg) ^ m7) * 4;
    int p1 = ((2 * kg + 1) ^ m7) * 4;

    // prologue: 2 stages in flight
    STAGE(0, 0);
    STAGE(1, 1);

    #pragma unroll
    for (int ks = 0; ks < 16; ks++) {
        // newest-4 outstanding = latest stage; waiting to 4 drains older incl.
        // tile ks. lgkmcnt(0) closes prior-iter ds_read vs DMA overwrite.
        asm volatile("s_waitcnt vmcnt(4) lgkmcnt(0)" ::: "memory");
        __builtin_amdgcn_s_barrier();

        // B loads first (older than the stage below -> compiler's pre-MFMA
        // B-wait leaves the newest stage in flight)
        half8 b[8];
        #pragma unroll
        for (int ni = 0; ni < 8; ni++) {
            int n = wc * 128 + ni * 16 + mrow;
            b[ni] = *(const half8*)(Bt + (size_t)n * 512 + ks * 32 + kg * 8);
        }

        if (ks < 14) STAGE((ks + 2) % 3, ks + 2);

        const float* lbuf = &lds[ks % 3][0];

        half8 a[4];
        #pragma unroll
        for (int mi = 0; mi < 4; mi++) {
            f32x4 lo = *(const f32x4*)&lbuf[rbase[mi] + p0];
            f32x4 hi = *(const f32x4*)&lbuf[rbase[mi] + p1];
            a[mi][0] = (_Float16)lo[0]; a[mi][1] = (_Float16)lo[1];
            a[mi][2] = (_Float16)lo[2]; a[mi][3] = (_Float16)lo[3];
            a[mi][4] = (_Float16)hi[0]; a[mi][5] = (_Float16)hi[1];
            a[mi][6] = (_Float16)hi[2]; a[mi][7] = (_Float16)hi[3];
        }

        #pragma unroll
        for (int mi = 0; mi < 4; mi++)
            #pragma unroll
            for (int ni = 0; ni < 8; ni++)
                acc[mi][ni] = __builtin_amdgcn_mfma_f32_16x16x32_f16(
                    a[mi], b[ni], acc[mi][ni], 0, 0, 0);
    }
    #undef STAGE

    #pragma unroll
    for (int mi = 0; mi < 4; mi++) {
        #pragma unroll
        for (int ni = 0; ni < 8; ni++) {
            int n = wc * 128 + ni * 16 + mrow;
            float bv = bias[n];
            #pragma unroll
            for (int rg = 0; rg < 4; rg++) {
                int row = bm + mi * 16 + kg * 4 + rg;
                if (row < M) {
                    float v = acc[mi][ni][rg] + bv;
                    C[(size_t)row * 256 + n] = (_Float16)fmaxf(v, 0.f);
                }
            }
        }
    }
}

// ---------------------------------------------------------------------------
// MLP layer 2: hmid @ W2 + b2 -> h and y0 = dinv*h, BOTH in channel-quarter
// layout [4][N][16] f16 (quarter q = channels 16q..16q+16; n>>4 == ni).
// ---------------------------------------------------------------------------

__global__ __launch_bounds__(256) void k_mlp2(
    const _Float16* __restrict__ A, const _Float16* __restrict__ Bt,
    const float* __restrict__ bias, const float* __restrict__ dinv,
    _Float16* __restrict__ Hq, _Float16* __restrict__ Yq, int M)
{
    int lane = threadIdx.x & 63;
    int wid  = threadIdx.x >> 6;
    int bm   = blockIdx.x * 256 + wid * 64;
    int mrow = lane & 15;
    int kg   = lane >> 4;
    size_t N16 = (size_t)M * 16;
    f32x4 acc[4][4] = {};

    int r[4];
    #pragma unroll
    for (int mi = 0; mi < 4; mi++) {
        int rr = bm + mi * 16 + mrow;
        r[mi] = rr < M ? rr : M - 1;
    }

    for (int k0 = 0; k0 < 256; k0 += 32) {
        int k = k0 + kg * 8;
        half8 a[4], b[4];
        #pragma unroll
        for (int mi = 0; mi < 4; mi++)
            a[mi] = *(const half8*)(A + (size_t)r[mi] * 256 + k);
        #pragma unroll
        for (int ni = 0; ni < 4; ni++) {
            int n = ni * 16 + mrow;
            b[ni] = *(const half8*)(Bt + (size_t)n * 256 + k);
        }
        #pragma unroll
        for (int mi = 0; mi < 4; mi++)
            #pragma unroll
            for (int ni = 0; ni < 4; ni++)
                acc[mi][ni] = __builtin_amdgcn_mfma_f32_16x16x32_f16(
                    a[mi], b[ni], acc[mi][ni], 0, 0, 0);
    }

    #pragma unroll
    for (int mi = 0; mi < 4; mi++) {
        #pragma unroll
        for (int ni = 0; ni < 4; ni++) {
            float bv = bias[ni * 16 + mrow];
            #pragma unroll
            for (int rg = 0; rg < 4; rg++) {
                int row = bm + mi * 16 + kg * 4 + rg;
                if (row < M) {
                    float v = acc[mi][ni][rg] + bv;
                    size_t o = (size_t)ni * N16 + (size_t)row * 16 + mrow;
                    Hq[o] = (_Float16)v;
                    Yq[o] = (_Float16)(v * dinv[row]);
                }
            }
        }
    }
}

// ---------------------------------------------------------------------------
// APPNP propagation, channel-quartered: y stored [4][N][16] f16; each quarter
// slice is 3.2MB -> replicable in every XCD's 4MiB L2 (gathers become L2-hot).
// One launch per iteration, q-major blockIdx for temporal pass separation.
// 512-thr blocks = 8 waves = 8 nodes; 2 lanes/edge x 16B -> 32 edges in
// flight per wave. LAST pass writes f32 out-quarters (log_softmax separate).
// ---------------------------------------------------------------------------

template <bool LAST>
__global__ __launch_bounds__(512) void k_propq(
    const int* __restrict__ rowptr, const int* __restrict__ csr_src,
    const float* __restrict__ dinv, const _Float16* __restrict__ Hq,
    const _Float16* __restrict__ Yq, _Float16* __restrict__ Ynq,
    float* __restrict__ Oq, int N, int qb)
{
    int q    = blockIdx.x / qb;
    int blk  = blockIdx.x - q * qb;
    int node = blk * 8 + (threadIdx.x >> 6);
    if (node >= N) return;
    int lane = threadIdx.x & 63;
    int s  = lane >> 1;        // edge slot 0..31
    int hh = lane & 1;         // channel half: 8 ch each

    size_t N16 = (size_t)N * 16;
    const _Float16* ybase = Yq + (size_t)q * N16;

    int beg = rowptr[node], end = rowptr[node + 1];
    float dn = dinv[node];
    half8 ys = *(const half8*)(ybase + (size_t)node * 16 + hh * 8);
    half8 hv = *(const half8*)(Hq + (size_t)q * N16 + (size_t)node * 16 + hh * 8);

    float acc[8] = {};
    for (int e = beg + s; e < end; e += 32) {
        int sidx = csr_src[e];
        half8 v = *(const half8*)(ybase + (size_t)sidx * 16 + hh * 8);
        #pragma unroll
        for (int c = 0; c < 8; c++) acc[c] += (float)v[c];
    }

    // reduce over the 32 edge slots (strides 2..32 preserve hh parity)
    #pragma unroll
    for (int c = 0; c < 8; c++) {
        float a = acc[c];
        a += __shfl_xor(a, 2);
        a += __shfl_xor(a, 4);
        a += __shfl_xor(a, 8);
        a += __shfl_xor(a, 16);
        a += __shfl_xor(a, 32);
        acc[c] = a;
    }

    float o[8];
    #pragma unroll
    for (int c = 0; c < 8; c++)
        o[c] = (1.0f - ALPHA) * dn * (acc[c] + (float)ys[c]) + ALPHA * (float)hv[c];

    if (s == 0) {              // lanes 0,1 hold the sums
        if (!LAST) {
            half8 w;
            #pragma unroll
            for (int c = 0; c < 8; c++) w[c] = (_Float16)(dn * o[c]);
            *(half8*)(Ynq + (size_t)q * N16 + (size_t)node * 16 + hh * 8) = w;
        } else {
            f32x4 w0, w1;
            #pragma unroll
            for (int c = 0; c < 4; c++) { w0[c] = o[c]; w1[c] = o[c + 4]; }
            float* p = Oq + (size_t)q * N16 + (size_t)node * 16 + hh * 8;
            *(f32x4*)p = w0;
            *(f32x4*)(p + 4) = w1;
        }
    }
}

// ---------------------------------------------------------------------------
// log_softmax over 64 classes from f32 out-quarters [4][N][16] -> d_out [N][64]
// ---------------------------------------------------------------------------

__global__ __launch_bounds__(256) void k_lsm(
    const float* __restrict__ Oq, float* __restrict__ out, int N)
{
    int node = blockIdx.x * 4 + (threadIdx.x >> 6);
    if (node >= N) return;
    int lane = threadIdx.x & 63;
    size_t N16 = (size_t)N * 16;
    float v = Oq[(size_t)(lane >> 4) * N16 + (size_t)node * 16 + (lane & 15)];
    float m = v;
    #pragma unroll
    for (int off = 32; off; off >>= 1) m = fmaxf(m, __shfl_xor(m, off));
    float ex = __expf(v - m);
    float s = ex;
    #pragma unroll
    for (int off = 32; off; off >>= 1) s += __shfl_xor(s, off);
    out[(size_t)node * 64 + lane] = v - m - logf(s);
}

// ---------------------------------------------------------------------------
// Launch
// ---------------------------------------------------------------------------

extern "C" void kernel_launch(void* const* d_in, const int* in_sizes, int n_in,
                              void* d_out, int out_size, void* d_ws, size_t ws_size,
                              hipStream_t stream) {
    const float* x  = (const float*)d_in[0];
    const int*   ei = (const int*)d_in[1];
    const float* W1 = (const float*)d_in[2];
    const float* b1 = (const float*)d_in[3];
    const float* W2 = (const float*)d_in[4];
    const float* b2 = (const float*)d_in[5];

    const int N = in_sizes[0] / C_IN;
    const int E = in_sizes[1] / 2;
    const int* src = ei;
    const int* dst = ei + E;

    char* ws = (char*)d_ws;
    size_t off = 0;
    auto alloc = [&](size_t bytes) -> void* {
        void* p = ws + off;
        off += (bytes + 255) & ~(size_t)255;
        return p;
    };

    int nb   = (N + SCAN_CHUNK - 1) / SCAN_CHUNK;
    int nbkt = (N + BKT_NODES - 1) / BKT_NODES;      // 196 for N=100000 (<=256 req'd)

    int*       counts  = (int*)      alloc((size_t)4 * N);
    int*       rowptr  = (int*)      alloc((size_t)4 * (N + 1));
    float*     dinv    = (float*)    alloc((size_t)4 * N);
    int*       bsum    = (int*)      alloc((size_t)4 * (nb + 1));
    int*       bcursor = (int*)      alloc((size_t)4 * nbkt);
    int*       csr_src = (int*)      alloc((size_t)4 * E);
    _Float16*  W1t     = (_Float16*) alloc((size_t)2 * C_IN * C_HID);
    _Float16*  W2t     = (_Float16*) alloc((size_t)2 * C_HID * C_OUT);
    _Float16*  hmid    = (_Float16*) alloc((size_t)2 * N * C_HID);   // 51.2 MB
    _Float16*  hq      = (_Float16*) alloc((size_t)2 * N * C_OUT);   // [4][N][16]
    _Float16*  ybuf0   = (_Float16*) alloc((size_t)2 * N * C_OUT);
    _Float16*  ybuf1   = (_Float16*) alloc((size_t)2 * N * C_OUT);
    _Float16*  ybuf2   = (_Float16*) alloc((size_t)2 * N * C_OUT);

    // bedges (38.5 MB) and the final f32 out-quarters (25.6 MB) both alias
    // hmid (51.2 MB): bedges dead after bscatter, hmid dead after mlp2.
    long long* bedges = (long long*)hmid;
    float*     oq     = (float*)hmid;

    // --- CSR build: bucket -> count -> scan -> scatter ---
    hipMemsetAsync(bcursor, 0, (size_t)4 * nbkt, stream);
    k_bucketA<<<(E + EPB - 1) / EPB, 256, 0, stream>>>(src, dst, E, bcursor, bedges, nbkt);
    k_bcount<<<nbkt, 256, 0, stream>>>(bcursor, bedges, counts, N);
    k_dinv<<<(N + 255) / 256, 256, 0, stream>>>(counts, dinv, N);
    k_scan1<<<nb, 256, 0, stream>>>(counts, N, bsum);
    k_scan2<<<1, 64, 0, stream>>>(bsum, nb, E, rowptr, N);
    k_scan3<<<nb, 256, 0, stream>>>(counts, N, bsum, rowptr);
    k_bscatter<<<nbkt, 256, 0, stream>>>(bcursor, bedges, rowptr, csr_src, N);

    // --- weight conversion + MLP (f16 MFMA) ---
    k_w1t<<<(C_IN * C_HID) / 256, 256, 0, stream>>>(W1, W1t);
    k_w2t<<<(C_HID * C_OUT) / 256, 256, 0, stream>>>(W2, W2t);
    k_mlp1<<<(N + 63) / 64, 128, 0, stream>>>(x, W1t, b1, hmid, N);
    k_mlp2<<<(N + 255) / 256, 256, 0, stream>>>(hmid, W2t, b2, dinv, hq, ybuf0, N);

    // --- propagation on y-quarters; final pass writes f32 out-quarters ---
    int qb = (N + 7) / 8;
    _Float16* ycur = ybuf0;
    for (int it = 0; it < K_STEPS - 1; ++it) {
        _Float16* ynxt = (it & 1) ? ybuf2 : ybuf1;
        k_propq<false><<<4 * qb, 512, 0, stream>>>(rowptr, csr_src, dinv, hq, ycur, ynxt, nullptr, N, qb);
        ycur = ynxt;
    }
    k_propq<true><<<4 * qb, 512, 0, stream>>>(rowptr, csr_src, dinv, hq, ycur, nullptr, oq, N, qb);

    // --- log_softmax: out-quarters -> d_out ---
    k_lsm<<<(N + 3) / 4, 256, 0, stream>>>(oq, (float*)d_out, N);
}

// Round 14
// 773.270 us; speedup vs baseline: 2.4656x; 2.4656x over previous
//
#include <hip/hip_runtime.h>
#include <hip/hip_bf16.h>

#define C_IN  512
#define C_HID 256
#define C_OUT 64
#define K_STEPS 10
#define ALPHA 0.1f

#define BKT_SHIFT 9          // 512 nodes per bucket
#define BKT_NODES 512
#define BCAP 24576           // per-bucket edge capacity (mean 16384 -> huge margin)
#define EPB 4096             // edges per block in pass A (16 per thread)

typedef _Float16 half8 __attribute__((ext_vector_type(8)));
typedef float f32x4 __attribute__((ext_vector_type(4)));

// ---------------------------------------------------------------------------
// CSR build via two-level counting sort (write-locality-friendly)
// ---------------------------------------------------------------------------

__global__ __launch_bounds__(256) void k_bucketA(
    const int* __restrict__ src, const int* __restrict__ dst, int E,
    int* __restrict__ bcursor, long long* __restrict__ bedges, int nbkt)
{
    __shared__ int lcount[256];
    __shared__ int lbase[256];
    int t = threadIdx.x;
    int base = blockIdx.x * EPB;
    for (int i = t; i < nbkt; i += 256) lcount[i] = 0;
    __syncthreads();

    int       mybkt[16];
    int       myoff[16];
    long long mypk[16];
    #pragma unroll
    for (int j = 0; j < 16; j++) {
        int e = base + j * 256 + t;          // coalesced
        if (e < E) {
            int s = src[e], d = dst[e];
            int b = d >> BKT_SHIFT;
            mybkt[j] = b;
            mypk[j]  = ((long long)d << 32) | (unsigned int)s;
            myoff[j] = atomicAdd(&lcount[b], 1);
        } else {
            mybkt[j] = -1;
        }
    }
    __syncthreads();
    for (int i = t; i < nbkt; i += 256)
        lbase[i] = lcount[i] ? atomicAdd(&bcursor[i], lcount[i]) : 0;
    __syncthreads();
    #pragma unroll
    for (int j = 0; j < 16; j++) {
        if (mybkt[j] >= 0) {
            int p = lbase[mybkt[j]] + myoff[j];
            bedges[(size_t)mybkt[j] * BCAP + p] = mypk[j];
        }
    }
}

__global__ __launch_bounds__(256) void k_bcount(
    const int* __restrict__ bcursor, const long long* __restrict__ bedges,
    int* __restrict__ counts, int N)
{
    __shared__ int lcnt[BKT_NODES];
    int b = blockIdx.x, t = threadIdx.x;
    int nodebase = b << BKT_SHIFT;
    for (int i = t; i < BKT_NODES; i += 256) lcnt[i] = 0;
    __syncthreads();
    int cnt = bcursor[b];
    const long long* be = bedges + (size_t)b * BCAP;
    for (int i = t; i < cnt; i += 256) {
        int d = (int)(be[i] >> 32);
        atomicAdd(&lcnt[d - nodebase], 1);
    }
    __syncthreads();
    for (int i = t; i < BKT_NODES; i += 256) {
        int node = nodebase + i;
        if (node < N) counts[node] = lcnt[i];
    }
}

__global__ __launch_bounds__(256) void k_bscatter(
    const int* __restrict__ bcursor, const long long* __restrict__ bedges,
    const int* __restrict__ rowptr, int* __restrict__ csr_src, int N)
{
    __shared__ int lcur[BKT_NODES];
    int b = blockIdx.x, t = threadIdx.x;
    int nodebase = b << BKT_SHIFT;
    for (int i = t; i < BKT_NODES; i += 256) {
        int node = nodebase + i;
        lcur[i] = (node < N) ? rowptr[node] : 0;
    }
    __syncthreads();
    int cnt = bcursor[b];
    const long long* be = bedges + (size_t)b * BCAP;
    for (int i = t; i < cnt; i += 256) {
        long long pk = be[i];
        int d = (int)(pk >> 32);
        int s = (int)pk;
        int p = atomicAdd(&lcur[d - nodebase], 1);
        csr_src[p] = s;
    }
}

// ---------------------------------------------------------------------------
// dinv + rowptr scan
// ---------------------------------------------------------------------------

__global__ void k_dinv(const int* __restrict__ counts, float* __restrict__ dinv, int N) {
    int i = blockIdx.x * blockDim.x + threadIdx.x;
    if (i < N) {
        float deg = (float)(counts[i] + 1);   // +1 self-loop
        dinv[i] = 1.0f / sqrtf(deg);
    }
}

#define SCAN_CHUNK 2048

__global__ void k_scan1(const int* __restrict__ counts, int N, int* __restrict__ bsum) {
    __shared__ int sdata[256];
    int b = blockIdx.x, t = threadIdx.x;
    int base = b * SCAN_CHUNK;
    int sum = 0;
    for (int i = t; i < SCAN_CHUNK; i += 256) {
        int idx = base + i;
        sum += (idx < N) ? counts[idx] : 0;
    }
    sdata[t] = sum;
    __syncthreads();
    for (int off = 128; off; off >>= 1) {
        if (t < off) sdata[t] += sdata[t + off];
        __syncthreads();
    }
    if (t == 0) bsum[b] = sdata[0];
}

__global__ void k_scan2(int* __restrict__ bsum, int nb, int E, int* __restrict__ rowptr, int N) {
    if (blockIdx.x == 0 && threadIdx.x == 0) {
        int run = 0;
        for (int i = 0; i < nb; i++) { int v = bsum[i]; bsum[i] = run; run += v; }
        rowptr[N] = E;
    }
}

__global__ void k_scan3(const int* __restrict__ counts, int N,
                        const int* __restrict__ bsum, int* __restrict__ rowptr) {
    __shared__ int sdata[256];
    int b = blockIdx.x, t = threadIdx.x;
    int base = b * SCAN_CHUNK;
    int vals[8];
    int local = 0;
    #pragma unroll
    for (int i = 0; i < 8; i++) {
        int idx = base + t * 8 + i;
        vals[i] = (idx < N) ? counts[idx] : 0;
        local += vals[i];
    }
    sdata[t] = local;
    __syncthreads();
    for (int off = 1; off < 256; off <<= 1) {
        int y = 0;
        if (t >= off) y = sdata[t - off];
        __syncthreads();
        sdata[t] += y;
        __syncthreads();
    }
    int excl = (t == 0) ? 0 : sdata[t - 1];
    int run = bsum[b] + excl;
    #pragma unroll
    for (int i = 0; i < 8; i++) {
        int idx = base + t * 8 + i;
        if (idx < N) rowptr[idx] = run;
        run += vals[i];
    }
}

// ---------------------------------------------------------------------------
// Weight pre-transpose + f16 conversion: W [K][N] f32 -> Wt [N][K] f16
// ---------------------------------------------------------------------------

__global__ void k_w1t(const float* __restrict__ W, _Float16* __restrict__ Wt) {
    int i = blockIdx.x * 256 + threadIdx.x;          // over 512*256
    int k = i >> 8, n = i & 255;
    Wt[(size_t)n * 512 + k] = (_Float16)W[i];
}

__global__ void k_w2t(const float* __restrict__ W, _Float16* __restrict__ Wt) {
    int i = blockIdx.x * 256 + threadIdx.x;          // over 256*64
    int k = i >> 6, n = i & 63;
    Wt[(size_t)n * 256 + k] = (_Float16)W[i];
}

// ---------------------------------------------------------------------------
// MLP layer 1 (counted-vmcnt pipeline, 128-thr blocks for stall decorrelation)
// hmid = relu(x @ W1 + b1). BM=64, BN=256 (x read ONCE), BK=32, 16 K-steps.
// 3 x 8KB LDS buffers; VGPR ~236 caps 2 waves/SIMD -> 4 blocks/CU with 4
// DECORRELATED barriers (vs r12's 2 blocks sharing one barrier domain each).
// acc[4][8]=128 AGPR on unified file; do NOT raise min-waves (r10 spill).
// ---------------------------------------------------------------------------

__global__ __launch_bounds__(128, 2) void k_mlp1(
    const float* __restrict__ A, const _Float16* __restrict__ Bt,
    const float* __restrict__ bias, _Float16* __restrict__ C, int M)
{
    __shared__ float lds[3][64 * 32];    // 3 x 8KB

    int t    = threadIdx.x;              // 0..127
    int lane = t & 63;
    int wc   = t >> 6;                   // wave col (0..1) -> cols 128*wc
    int bm   = blockIdx.x * 64;
    int mrow = lane & 15;
    int kg   = lane >> 4;                // 0..3

    // staging: LDS chunk (q*128 + t) <- row r = q*16 + (t>>3), pos c = t&7,
    // src chunk cg = c ^ (r&7) = (t&7) ^ ((t>>3)&7)   (q*16 = 0 mod 8)
    int srow = t >> 3;                   // 0..15, + 16*q
    int cgs  = (t & 7) ^ ((t >> 3) & 7);

    const float* gsrc[4];
    #pragma unroll
    for (int q = 0; q < 4; q++) {
        int gr = bm + q * 16 + srow;
        if (gr >= M) gr = M - 1;         // clamp: no OOB reads, rows discarded at C-write
        gsrc[q] = A + (size_t)gr * 512 + cgs * 4;
    }

    #define STAGE(buf, ks)                                                       \
        {                                                                        \
            _Pragma("unroll")                                                    \
            for (int q = 0; q < 4; q++) {                                        \
                __builtin_amdgcn_global_load_lds(                                \
                    (const __attribute__((address_space(1))) void*)(gsrc[q] + (ks) * 32), \
                    (__attribute__((address_space(3))) void*)((char*)&lds[buf][0] + q * 2048 + t * 16), \
                    16, 0, 0);                                                   \
            }                                                                    \
        }

    f32x4 acc[4][8] = {};

    // read-side swizzle: row_local&7 == mrow&7 for all mi (offsets mult of 8)
    int m7 = lane & 7;
    int rbase[4];
    #pragma unroll
    for (int mi = 0; mi < 4; mi++)
        rbase[mi] = (mi * 16 + mrow) * 32;
    int p0 = ((2 * kg) ^ m7) * 4;
    int p1 = ((2 * kg + 1) ^ m7) * 4;

    // prologue: 2 stages in flight
    STAGE(0, 0);
    STAGE(1, 1);

    #pragma unroll
    for (int ks = 0; ks < 16; ks++) {
        // newest-4 outstanding = latest stage; waiting to 4 drains older incl.
        // tile ks. lgkmcnt(0) closes prior-iter ds_read vs DMA overwrite.
        asm volatile("s_waitcnt vmcnt(4) lgkmcnt(0)" ::: "memory");
        __builtin_amdgcn_s_barrier();

        // B loads first (older than the stage below -> compiler's pre-MFMA
        // B-wait leaves the newest stage in flight)
        half8 b[8];
        #pragma unroll
        for (int ni = 0; ni < 8; ni++) {
            int n = wc * 128 + ni * 16 + mrow;
            b[ni] = *(const half8*)(Bt + (size_t)n * 512 + ks * 32 + kg * 8);
        }

        if (ks < 14) STAGE((ks + 2) % 3, ks + 2);

        const float* lbuf = &lds[ks % 3][0];

        half8 a[4];
        #pragma unroll
        for (int mi = 0; mi < 4; mi++) {
            f32x4 lo = *(const f32x4*)&lbuf[rbase[mi] + p0];
            f32x4 hi = *(const f32x4*)&lbuf[rbase[mi] + p1];
            a[mi][0] = (_Float16)lo[0]; a[mi][1] = (_Float16)lo[1];
            a[mi][2] = (_Float16)lo[2]; a[mi][3] = (_Float16)lo[3];
            a[mi][4] = (_Float16)hi[0]; a[mi][5] = (_Float16)hi[1];
            a[mi][6] = (_Float16)hi[2]; a[mi][7] = (_Float16)hi[3];
        }

        #pragma unroll
        for (int mi = 0; mi < 4; mi++)
            #pragma unroll
            for (int ni = 0; ni < 8; ni++)
                acc[mi][ni] = __builtin_amdgcn_mfma_f32_16x16x32_f16(
                    a[mi], b[ni], acc[mi][ni], 0, 0, 0);
    }
    #undef STAGE

    #pragma unroll
    for (int mi = 0; mi < 4; mi++) {
        #pragma unroll
        for (int ni = 0; ni < 8; ni++) {
            int n = wc * 128 + ni * 16 + mrow;
            float bv = bias[n];
            #pragma unroll
            for (int rg = 0; rg < 4; rg++) {
                int row = bm + mi * 16 + kg * 4 + rg;
                if (row < M) {
                    float v = acc[mi][ni][rg] + bv;
                    C[(size_t)row * 256 + n] = (_Float16)fmaxf(v, 0.f);
                }
            }
        }
    }
}

// ---------------------------------------------------------------------------
// MLP layer 2: h[M][64] f16 = hmid[M][256] f16 @ W2 + b2; also y0 = dinv*h
// ---------------------------------------------------------------------------

__global__ __launch_bounds__(256) void k_mlp2(
    const _Float16* __restrict__ A, const _Float16* __restrict__ Bt,
    const float* __restrict__ bias, const float* __restrict__ dinv,
    _Float16* __restrict__ C, _Float16* __restrict__ Y, int M)
{
    int lane = threadIdx.x & 63;
    int wid  = threadIdx.x >> 6;
    int bm   = blockIdx.x * 256 + wid * 64;
    int mrow = lane & 15;
    int kg   = lane >> 4;
    f32x4 acc[4][4] = {};

    int r[4];
    #pragma unroll
    for (int mi = 0; mi < 4; mi++) {
        int rr = bm + mi * 16 + mrow;
        r[mi] = rr < M ? rr : M - 1;
    }

    for (int k0 = 0; k0 < 256; k0 += 32) {
        int k = k0 + kg * 8;
        half8 a[4], b[4];
        #pragma unroll
        for (int mi = 0; mi < 4; mi++)
            a[mi] = *(const half8*)(A + (size_t)r[mi] * 256 + k);
        #pragma unroll
        for (int ni = 0; ni < 4; ni++) {
            int n = ni * 16 + mrow;
            b[ni] = *(const half8*)(Bt + (size_t)n * 256 + k);
        }
        #pragma unroll
        for (int mi = 0; mi < 4; mi++)
            #pragma unroll
            for (int ni = 0; ni < 4; ni++)
                acc[mi][ni] = __builtin_amdgcn_mfma_f32_16x16x32_f16(
                    a[mi], b[ni], acc[mi][ni], 0, 0, 0);
    }

    #pragma unroll
    for (int mi = 0; mi < 4; mi++) {
        #pragma unroll
        for (int ni = 0; ni < 4; ni++) {
            int n = ni * 16 + mrow;
            float bv = bias[n];
            #pragma unroll
            for (int rg = 0; rg < 4; rg++) {
                int row = bm + mi * 16 + kg * 4 + rg;
                if (row < M) {
                    float v = acc[mi][ni][rg] + bv;
                    C[(size_t)row * 64 + n] = (_Float16)v;
                    Y[(size_t)row * 64 + n] = (_Float16)(v * dinv[row]);
                }
            }
        }
    }
}

// ---------------------------------------------------------------------------
// APPNP propagation on scaled state y = dinv * out (weightless gathers).
// One wave per dst node; 8 lanes per edge (16B -> one 128B line per edge).
// Single MASKED 32-edge pass per iteration (clamped index + 0/1 weight):
// all 4 gathers always in flight, no serial tail (deg ~ Poisson(32)).
// Last iteration fuses log_softmax and writes f32 d_out.
// [r13 lesson: channel-quartering regressed 3.5x -- 32B granules quadruple
//  request rate and concurrent quarters+csr streaming thrash L2. Full-row
//  128B/edge at ~7.7 TB/s effective is the right shape.]
// ---------------------------------------------------------------------------

template <bool LAST>
__global__ __launch_bounds__(256) void k_prop(
    const int* __restrict__ rowptr, const int* __restrict__ csr_src,
    const float* __restrict__ dinv, const _Float16* __restrict__ h,
    const _Float16* __restrict__ ycur, _Float16* __restrict__ ynxt,
    float* __restrict__ out, int N)
{
    int node = blockIdx.x * 4 + (threadIdx.x >> 6);
    if (node >= N) return;
    int lane = threadIdx.x & 63;
    int g  = lane >> 3;       // edge slot 0..7
    int cg = lane & 7;        // channel group: channels [8*cg, 8*cg+8)

    int beg = rowptr[node], end = rowptr[node + 1];
    // hoist tail operands so their latency hides under the edge loop
    float dn = dinv[node];
    half8 ys = *(const half8*)(ycur + ((size_t)node << 6) + cg * 8);
    half8 hv = *(const half8*)(h    + ((size_t)node << 6) + cg * 8);

    float acc[8] = {};
    for (int e = beg + g; e < end; e += 32) {
        int i1 = e + 8, i2 = e + 16, i3 = e + 24;
        float p1 = (i1 < end) ? 1.f : 0.f;
        float p2 = (i2 < end) ? 1.f : 0.f;
        float p3 = (i3 < end) ? 1.f : 0.f;
        int s0 = csr_src[e];
        int s1 = csr_src[(i1 < end) ? i1 : e];
        int s2 = csr_src[(i2 < end) ? i2 : e];
        int s3 = csr_src[(i3 < end) ? i3 : e];
        half8 v0 = *(const half8*)(ycur + ((size_t)s0 << 6) + cg * 8);
        half8 v1 = *(const half8*)(ycur + ((size_t)s1 << 6) + cg * 8);
        half8 v2 = *(const half8*)(ycur + ((size_t)s2 << 6) + cg * 8);
        half8 v3 = *(const half8*)(ycur + ((size_t)s3 << 6) + cg * 8);
        #pragma unroll
        for (int c = 0; c < 8; c++)
            acc[c] += ((float)v0[c] + p1 * (float)v1[c])
                    + (p2 * (float)v2[c] + p3 * (float)v3[c]);
    }

    // reduce the 8 edge slots
    #pragma unroll
    for (int c = 0; c < 8; c++) {
        float a = acc[c];
        a += __shfl_xor(a, 8);
        a += __shfl_xor(a, 16);
        a += __shfl_xor(a, 32);
        acc[c] = a;
    }

    float o[8];
    #pragma unroll
    for (int c = 0; c < 8; c++)
        o[c] = (1.0f - ALPHA) * dn * (acc[c] + (float)ys[c]) + ALPHA * (float)hv[c];

    if (!LAST) {
        if (g == 0) {
            half8 w;
            #pragma unroll
            for (int c = 0; c < 8; c++) w[c] = (_Float16)(dn * o[c]);
            *(half8*)(ynxt + ((size_t)node << 6) + cg * 8) = w;
        }
    } else {
        float m = o[0];
        #pragma unroll
        for (int c = 1; c < 8; c++) m = fmaxf(m, o[c]);
        m = fmaxf(m, __shfl_xor(m, 1));
        m = fmaxf(m, __shfl_xor(m, 2));
        m = fmaxf(m, __shfl_xor(m, 4));
        float s = 0.f;
        #pragma unroll
        for (int c = 0; c < 8; c++) s += __expf(o[c] - m);
        s += __shfl_xor(s, 1);
        s += __shfl_xor(s, 2);
        s += __shfl_xor(s, 4);
        float ls = m + logf(s);
        if (g == 0) {
            f32x4 w0, w1;
            #pragma unroll
            for (int c = 0; c < 4; c++) { w0[c] = o[c] - ls; w1[c] = o[c + 4] - ls; }
            float* p = out + ((size_t)node << 6) + cg * 8;
            *(f32x4*)p = w0;
            *(f32x4*)(p + 4) = w1;
        }
    }
}

// ---------------------------------------------------------------------------
// Launch
// ---------------------------------------------------------------------------

extern "C" void kernel_launch(void* const* d_in, const int* in_sizes, int n_in,
                              void* d_out, int out_size, void* d_ws, size_t ws_size,
                              hipStream_t stream) {
    const float* x  = (const float*)d_in[0];
    const int*   ei = (const int*)d_in[1];
    const float* W1 = (const float*)d_in[2];
    const float* b1 = (const float*)d_in[3];
    const float* W2 = (const float*)d_in[4];
    const float* b2 = (const float*)d_in[5];

    const int N = in_sizes[0] / C_IN;
    const int E = in_sizes[1] / 2;
    const int* src = ei;
    const int* dst = ei + E;

    char* ws = (char*)d_ws;
    size_t off = 0;
    auto alloc = [&](size_t bytes) -> void* {
        void* p = ws + off;
        off += (bytes + 255) & ~(size_t)255;
        return p;
    };

    int nb   = (N + SCAN_CHUNK - 1) / SCAN_CHUNK;
    int nbkt = (N + BKT_NODES - 1) / BKT_NODES;      // 196 for N=100000 (<=256 req'd)

    int*       counts  = (int*)      alloc((size_t)4 * N);
    int*       rowptr  = (int*)      alloc((size_t)4 * (N + 1));
    float*     dinv    = (float*)    alloc((size_t)4 * N);
    int*       bsum    = (int*)      alloc((size_t)4 * (nb + 1));
    int*       bcursor = (int*)      alloc((size_t)4 * nbkt);
    int*       csr_src = (int*)      alloc((size_t)4 * E);
    _Float16*  W1t     = (_Float16*) alloc((size_t)2 * C_IN * C_HID);
    _Float16*  W2t     = (_Float16*) alloc((size_t)2 * C_HID * C_OUT);
    _Float16*  hmid    = (_Float16*) alloc((size_t)2 * N * C_HID);   // 51.2 MB
    _Float16*  h       = (_Float16*) alloc((size_t)2 * N * C_OUT);
    _Float16*  ybuf0   = (_Float16*) alloc((size_t)2 * N * C_OUT);
    _Float16*  ybuf1   = (_Float16*) alloc((size_t)2 * N * C_OUT);
    _Float16*  ybuf2   = (_Float16*) alloc((size_t)2 * N * C_OUT);

    // bedges (nbkt*BCAP*8B = 38.5 MB) aliases hmid (51.2 MB): all bucket
    // passes complete (in-stream) before k_mlp1 writes hmid.
    long long* bedges = (long long*)hmid;

    // --- CSR build: bucket -> count -> scan -> scatter ---
    hipMemsetAsync(bcursor, 0, (size_t)4 * nbkt, stream);
    k_bucketA<<<(E + EPB - 1) / EPB, 256, 0, stream>>>(src, dst, E, bcursor, bedges, nbkt);
    k_bcount<<<nbkt, 256, 0, stream>>>(bcursor, bedges, counts, N);
    k_dinv<<<(N + 255) / 256, 256, 0, stream>>>(counts, dinv, N);
    k_scan1<<<nb, 256, 0, stream>>>(counts, N, bsum);
    k_scan2<<<1, 64, 0, stream>>>(bsum, nb, E, rowptr, N);
    k_scan3<<<nb, 256, 0, stream>>>(counts, N, bsum, rowptr);
    k_bscatter<<<nbkt, 256, 0, stream>>>(bcursor, bedges, rowptr, csr_src, N);

    // --- weight conversion + MLP (f16 MFMA) ---
    k_w1t<<<(C_IN * C_HID) / 256, 256, 0, stream>>>(W1, W1t);
    k_w2t<<<(C_HID * C_OUT) / 256, 256, 0, stream>>>(W2, W2t);
    k_mlp1<<<(N + 63) / 64, 128, 0, stream>>>(x, W1t, b1, hmid, N);
    k_mlp2<<<(N + 255) / 256, 256, 0, stream>>>(hmid, W2t, b2, dinv, h, ybuf0, N);

    // --- propagation on y; last iteration fuses log_softmax ---
    int pgrid = (N + 3) / 4;
    _Float16* ycur = ybuf0;
    for (int it = 0; it < K_STEPS - 1; ++it) {
        _Float16* ynxt = (it & 1) ? ybuf2 : ybuf1;
        k_prop<false><<<pgrid, 256, 0, stream>>>(rowptr, csr_src, dinv, h, ycur, ynxt, nullptr, N);
        ycur = ynxt;
    }
    k_prop<true><<<pgrid, 256, 0, stream>>>(rowptr, csr_src, dinv, h, ycur, nullptr, (float*)d_out, N);
}